// Round 7
// baseline (127.881 us; speedup 1.0000x reference)
//
#include <hip/hip_runtime.h>

#define N 64
#define NC 128
#define NB 8
#define LSEQ 4096
#define QC 128
#define NCHUNK 32

// fp32 regions (float offsets into ws)
#define OFF_ABAR 0
#define OFF_AQ   4096
#define OFF_BBAR 8192          // [n][c] 64x128
#define OFF_ABT  16384
#define OFF_A4   20480
#define OFF_A4T  24576
#define OFF_FS   36864         // (region reserved; unused by fused path)
#define U16_BASE (OFF_FS + NCHUNK*NB*NC*N)

// u16 offsets (in u16 units) relative to u16b = (unsigned short*)(ws + U16_BASE)
#define OFF_WH 0                       // [c][n][kq] 128x64x128, kq = 127-p
#define OFF_WL (OFF_WH + NC*N*QC)
#define OFF_UH (OFF_WL + NC*N*QC)      // [c][q][n]
#define OFF_UL (OFF_UH + NC*QC*N)
#define OFF_KH (OFF_UL + NC*QC*N)      // [c][256] reversed-extended k
#define OFF_KL (OFF_KH + NC*256)
#define OFF_SH (OFF_KL + NC*256)       // [slot][b][c][n], slot j holds S_j (slot0=0)
#define OFF_SL (OFF_SH + NCHUNK*NB*NC*N)

typedef __attribute__((ext_vector_type(8)))  __bf16 bf16x8;
typedef __attribute__((ext_vector_type(16))) float  f32x16;
typedef __attribute__((ext_vector_type(4)))  unsigned int u32x4;

__device__ __forceinline__ float rdlane(float v, int l) {
    return __int_as_float(__builtin_amdgcn_readlane(__float_as_int(v), l));
}

__device__ __forceinline__ void load_row64(const float* __restrict__ p, float (&ar)[64]) {
    const float4* rp = reinterpret_cast<const float4*>(p);
#pragma unroll
    for (int t = 0; t < 16; ++t) {
        float4 v = rp[t];
        ar[4*t+0] = v.x; ar[4*t+1] = v.y; ar[4*t+2] = v.z; ar[4*t+3] = v.w;
    }
}

__device__ __forceinline__ float matvec64(const float (&ar)[64], float v) {
    float a0 = 0.f, a1 = 0.f, a2 = 0.f, a3 = 0.f;
#pragma unroll
    for (int m = 0; m < 64; m += 4) {
        a0 += ar[m+0] * rdlane(v, m+0);
        a1 += ar[m+1] * rdlane(v, m+1);
        a2 += ar[m+2] * rdlane(v, m+2);
        a3 += ar[m+3] * rdlane(v, m+3);
    }
    return (a0 + a1) + (a2 + a3);
}

// fp32 -> (hi, lo) bf16 pair, RNE both
__device__ __forceinline__ void f2bf_hl(float x, unsigned short& hi, unsigned short& lo) {
    unsigned u = __float_as_uint(x);
    unsigned r = (u + 0x7fffu + ((u >> 16) & 1u)) >> 16;
    hi = (unsigned short)r;
    float fh = __uint_as_float(r << 16);
    float l  = x - fh;
    unsigned ul = __float_as_uint(l);
    unsigned rl = (ul + 0x7fffu + ((ul >> 16) & 1u)) >> 16;
    lo = (unsigned short)rl;
}

__device__ __forceinline__ unsigned pack_hl2(float x0, float x1, unsigned& lo32) {
    unsigned short h0, l0, h1, l1;
    f2bf_hl(x0, h0, l0); f2bf_hl(x1, h1, l1);
    lo32 = (unsigned)l0 | ((unsigned)l1 << 16);
    return (unsigned)h0 | ((unsigned)h1 << 16);
}

__device__ __forceinline__ bf16x8 ld_frag(const unsigned short* p) {
    u32x4 v = *(const u32x4*)p;
    return __builtin_bit_cast(bf16x8, v);
}

__device__ __forceinline__ bf16x8 pack8(const unsigned short* v) {
    u32x4 u;
    u.x = v[0] | ((unsigned)v[1] << 16);
    u.y = v[2] | ((unsigned)v[3] << 16);
    u.z = v[4] | ((unsigned)v[5] << 16);
    u.w = v[6] | ((unsigned)v[7] << 16);
    return __builtin_bit_cast(bf16x8, u);
}

// ---------------------------------------------------------------------------
// setup: single block, 1024 threads (16 waves).
//   stage1: 64 forward-subst column solves -> A_bar
//   stage2: A_bar^2 cols; B_bar = dt/2 (A_bar B + B)   [(I-hA)^-1 = (A_bar+I)/2]
//   stage3: A_bar^4 cols -> ws
// ---------------------------------------------------------------------------
__global__ __launch_bounds__(1024) void setup_kernel(const float* __restrict__ A,
    const float* __restrict__ B, const float* __restrict__ dtp, float* __restrict__ ws)
{
    __shared__ float AT[64*65];    // A^T; reused as A2 (row-major) in stage2
    __shared__ float Ab[64*65];    // A_bar row-major
    __shared__ float AbT[64*65];
    __shared__ float A2T[64*65];
    const int tid = threadIdx.x;
    const int wv  = tid >> 6;      // 0..15
    const int l   = tid & 63;
    const float dt = dtp[0];
    const float h  = 0.5f * dt;

    for (int idx = tid; idx < 4096; idx += 1024) {
        int row = idx >> 6, i = idx & 63;
        AT[i*65 + row] = A[idx];
    }
    __syncthreads();
    const float rdv = 1.0f / (1.0f - h * AT[l*65 + l]);

#pragma unroll 1
    for (int rep = 0; rep < 4; ++rep) {
        const int j = wv + rep*16;
        float r = ((l == j) ? 1.0f : 0.0f) + h * AT[j*65 + l];
#pragma unroll
        for (int i = 0; i < 64; ++i) {
            float xi = rdlane(r, i) * rdlane(rdv, i);
            r = fmaf(h * xi, AT[i*65 + l], r);
            r = (l == i) ? xi : r;
        }
        Ab[l*65 + j]  = r;
        AbT[j*65 + l] = r;
    }
    __syncthreads();

    for (int idx = tid; idx < 4096; idx += 1024) {
        int i = idx >> 6, j = idx & 63;
        ws[OFF_ABAR + idx] = Ab[i*65 + j];
        ws[OFF_ABT + idx]  = AbT[i*65 + j];
    }
    float ar[64];
#pragma unroll
    for (int m2 = 0; m2 < 64; ++m2) ar[m2] = Ab[l*65 + m2];

#pragma unroll 1
    for (int rep = 0; rep < 4; ++rep) {
        const int j = wv + rep*16;
        float v = AbT[j*65 + l];
        float y = matvec64(ar, v);
        AT[l*65 + j]  = y;          // A2 row-major
        A2T[j*65 + l] = y;
    }
#pragma unroll 1
    for (int rep = 0; rep < 8; ++rep) {
        const int c = wv + rep*16;
        float v = B[l*NC + c];
        float y = matvec64(ar, v);
        ws[OFF_BBAR + l*NC + c] = h * (y + v);
    }
    __syncthreads();

    float a2r[64];
#pragma unroll
    for (int m2 = 0; m2 < 64; ++m2) a2r[m2] = AT[l*65 + m2];
#pragma unroll 1
    for (int rep = 0; rep < 4; ++rep) {
        const int j = wv + rep*16;
        float v = A2T[j*65 + l];
        float y = matvec64(a2r, v);
        ws[OFF_A4 + l*64 + j]  = y;
        ws[OFF_A4T + j*64 + l] = y;
    }
}

// ---------------------------------------------------------------------------
// chains: stride-4 chains with A^4 / (A^4)^T. 4 waves per block.
// ---------------------------------------------------------------------------
__global__ __launch_bounds__(256, 1) void chains_kernel(const float* __restrict__ C,
    float* __restrict__ ws)
{
    __shared__ float Wlds[128][65];
    __shared__ float karr[128];
    __shared__ float seed[3][64];
    unsigned short* u16b = (unsigned short*)(ws + U16_BASE);
    const int bid = blockIdx.x;
    const int tid = threadIdx.x;
    const int w4  = tid >> 6;
    const int l   = tid & 63;

    if (bid < 128) {                       // ---- W chain + k, channel c
        const int c = bid;
        float a4[64];
        load_row64(ws + OFF_A4 + l*64, a4);
        const float Cl = C[l*NC + c];
        float cur;
        if (w4 == 0) {
            float ab[64];
            load_row64(ws + OFF_ABAR + l*64, ab);
            float t = ws[OFF_BBAR + l*NC + c];
            cur = t;
            t = matvec64(ab, t); seed[0][l] = t;
            t = matvec64(ab, t); seed[1][l] = t;
            t = matvec64(ab, t); seed[2][l] = t;
        }
        __syncthreads();
        if (w4 > 0) cur = seed[w4 - 1][l];
        int p = w4;
#pragma unroll 1
        for (int it = 0; it < 32; ++it) {
            Wlds[p][l] = cur;
            float d = Cl * cur;
            d += __shfl_xor(d, 32, 64); d += __shfl_xor(d, 16, 64);
            d += __shfl_xor(d, 8, 64);  d += __shfl_xor(d, 4, 64);
            d += __shfl_xor(d, 2, 64);  d += __shfl_xor(d, 1, 64);
            if (l == 0) karr[p] = d;
            if (it < 31) { cur = matvec64(a4, cur); p += 4; }
        }
        __syncthreads();
        for (int idx = tid; idx < 64*64; idx += 256) {
            int n = idx >> 6, i2 = idx & 63;
            int kq = i2*2;
            float w0 = Wlds[127 - kq][n];
            float w1 = Wlds[126 - kq][n];
            unsigned lo32, hi32 = pack_hl2(w0, w1, lo32);
            ((unsigned*)(u16b + OFF_WH + (c*64 + n)*128))[i2] = hi32;
            ((unsigned*)(u16b + OFF_WL + (c*64 + n)*128))[i2] = lo32;
        }
        if (tid < 128) {
            int i = tid;
            float k0 = (2*i   < 128) ? karr[127 - 2*i] : 0.0f;
            float k1 = (2*i+1 < 128) ? karr[126 - 2*i] : 0.0f;
            unsigned lo32, hi32 = pack_hl2(k0, k1, lo32);
            ((unsigned*)(u16b + OFF_KH + c*256))[i] = hi32;
            ((unsigned*)(u16b + OFF_KL + c*256))[i] = lo32;
        }
    } else if (bid < 256) {                // ---- U chain, channel c
        const int c = bid - 128;
        float a4t[64];
        load_row64(ws + OFF_A4T + l*64, a4t);
        float cur;
        if (w4 == 0) {
            float abt[64];
            load_row64(ws + OFF_ABT + l*64, abt);
            float t = C[l*NC + c];
            t = matvec64(abt, t); cur = t;
            t = matvec64(abt, t); seed[0][l] = t;
            t = matvec64(abt, t); seed[1][l] = t;
            t = matvec64(abt, t); seed[2][l] = t;
        }
        __syncthreads();
        if (w4 > 0) cur = seed[w4 - 1][l];
        int q = w4;
#pragma unroll 1
        for (int it = 0; it < 32; ++it) {
            unsigned short hi, lo; f2bf_hl(cur, hi, lo);
            u16b[OFF_UH + (c*QC + q)*64 + l] = hi;
            u16b[OFF_UL + (c*QC + q)*64 + l] = lo;
            if (it < 31) { cur = matvec64(a4t, cur); q += 4; }
        }
    } else {                               // ---- AQ columns (fp32)
        const int j = (bid - 256)*4 + w4;
        float a4[64];
        load_row64(ws + OFF_A4 + l*64, a4);
        float cur = (l == j) ? 1.0f : 0.0f;
#pragma unroll 1
        for (int it = 0; it < 32; ++it) cur = matvec64(a4, cur);
        ws[OFF_AQ + l*64 + j] = cur;
    }
}

// ---------------------------------------------------------------------------
// fused: one block per channel c, 512 threads (8 waves).
//   per g in 0..3: stage X(c,g) once; waves 0-3: F = Wrev@X -> F_lds;
//                  waves 4-7: conv = T@X -> out (plain store)
//   then: 8 in-block scans (wave = batch b) over F_lds -> SH/SL
// ---------------------------------------------------------------------------
__global__ __launch_bounds__(512) void fused_kernel(const float* __restrict__ x,
    float* __restrict__ ws, float* __restrict__ out)
{
    __shared__ float F_lds[NCHUNK*NB*64];                  // 64 KB, [j][b][n]
    __shared__ __align__(16) unsigned Xh32[64*68], Xl32[64*68];
    __shared__ __align__(16) unsigned krh32[128], krl32[128];
    unsigned short* u16b = (unsigned short*)(ws + U16_BASE);
    const int tid = threadIdx.x;
    const int c = blockIdx.x;
    const int w = tid >> 6;
    const int l = tid & 63;
    const int lane2 = l & 31;
    const int h = l >> 5;

    if (tid < 128) {
        krh32[tid] = ((const unsigned*)(u16b + OFF_KH + c*256))[tid];
        krl32[tid] = ((const unsigned*)(u16b + OFF_KL + c*256))[tid];
    }
    const unsigned short* Xh = (const unsigned short*)Xh32;
    const unsigned short* Xl = (const unsigned short*)Xl32;
    const unsigned short* krh = (const unsigned short*)krh32;
    const unsigned short* krl = (const unsigned short*)krl32;

#pragma unroll 1
    for (int g = 0; g < 4; ++g) {
        __syncthreads();   // previous g's readers done; kr staged (g=0)
        for (int idx = tid; idx < 64*64; idx += 512) {
            int col = idx >> 6, i2 = idx & 63;
            int j = g*8 + (col >> 3), b = col & 7;
            const float2 xv = *reinterpret_cast<const float2*>(
                x + ((long)(b*NC + c))*LSEQ + j*QC + i2*2);
            unsigned lo32, hi32 = pack_hl2(xv.x, xv.y, lo32);
            Xh32[col*68 + i2] = hi32;
            Xl32[col*68 + i2] = lo32;
        }
        __syncthreads();

        if (w < 4) {
            // ---- F = Wrev @ X, quadrant (mt, ntf)
            const int mt = w & 1, ntf = w >> 1;
            const unsigned short* WHp = u16b + OFF_WH + (c*64 + mt*32 + lane2)*128 + 8*h;
            const unsigned short* WLp = u16b + OFF_WL + (c*64 + mt*32 + lane2)*128 + 8*h;
            f32x16 f0 = {}, f1 = {}, f2 = {};
#pragma unroll
            for (int t = 0; t < 8; ++t) {
                bf16x8 ah = ld_frag(WHp + 16*t);
                bf16x8 al = ld_frag(WLp + 16*t);
                bf16x8 bh = ld_frag(&Xh[(ntf*32 + lane2)*136 + 16*t + 8*h]);
                bf16x8 bl = ld_frag(&Xl[(ntf*32 + lane2)*136 + 16*t + 8*h]);
                f0 = __builtin_amdgcn_mfma_f32_32x32x16_bf16(ah, bh, f0, 0, 0, 0);
                f1 = __builtin_amdgcn_mfma_f32_32x32x16_bf16(al, bh, f1, 0, 0, 0);
                f2 = __builtin_amdgcn_mfma_f32_32x32x16_bf16(ah, bl, f2, 0, 0, 0);
            }
            f32x16 s = f0 + f1 + f2;
            const int col = ntf*32 + lane2;          // local col within g
            const int j = g*8 + (col >> 3), b = col & 7;
#pragma unroll
            for (int r = 0; r < 16; ++r) {
                int n = mt*32 + (r & 3) + 8*(r >> 2) + 4*h;
                F_lds[(j*NB + b)*64 + n] = s[r];
            }
        } else {
            // ---- conv term: Y = T @ X, m-tile (w-4), both nt -> out
            const int m = (w - 4)*32 + lane2;
            f32x16 a0[2] = {{}, {}}, a1[2] = {{}, {}}, a2[2] = {{}, {}};
#pragma unroll
            for (int t = 0; t < 8; ++t) {
                int I0 = 127 - m + 16*t + 8*h;
                unsigned short vh[8], vl[8];
#pragma unroll
                for (int e = 0; e < 8; ++e) { vh[e] = krh[I0 + e]; vl[e] = krl[I0 + e]; }
                bf16x8 ah = pack8(vh), al = pack8(vl);
#pragma unroll
                for (int nt = 0; nt < 2; ++nt) {
                    bf16x8 bh = ld_frag(&Xh[(nt*32 + lane2)*136 + 16*t + 8*h]);
                    bf16x8 bl = ld_frag(&Xl[(nt*32 + lane2)*136 + 16*t + 8*h]);
                    a0[nt] = __builtin_amdgcn_mfma_f32_32x32x16_bf16(ah, bh, a0[nt], 0, 0, 0);
                    a1[nt] = __builtin_amdgcn_mfma_f32_32x32x16_bf16(al, bh, a1[nt], 0, 0, 0);
                    a2[nt] = __builtin_amdgcn_mfma_f32_32x32x16_bf16(ah, bl, a2[nt], 0, 0, 0);
                }
            }
#pragma unroll
            for (int nt = 0; nt < 2; ++nt) {
                f32x16 s = a0[nt] + a1[nt] + a2[nt];
                int col = g*64 + nt*32 + lane2;
                int j = col >> 3, b = col & 7;
                float* op = out + ((long)(b*NC + c))*LSEQ + j*QC;
#pragma unroll
                for (int r = 0; r < 16; ++r) {
                    int row = (w - 4)*32 + (r & 3) + 8*(r >> 2) + 4*h;
                    op[row] = s[r];
                }
            }
        }
    }
    __syncthreads();

    // ---- scan: wave w = batch b, chain over 32 chunks from F_lds
    {
        const int b = w;
        float aq[64];
        load_row64(ws + OFF_AQ + l*64, aq);

        u16b[OFF_SH + ((0*NB + b)*NC + c)*64 + l] = 0;   // S_0 = 0
        u16b[OFF_SL + ((0*NB + b)*NC + c)*64 + l] = 0;
        float s = F_lds[(0*NB + b)*64 + l];              // S_1 = F_0
        {
            unsigned short hi, lo; f2bf_hl(s, hi, lo);
            u16b[OFF_SH + ((1*NB + b)*NC + c)*64 + l] = hi;
            u16b[OFF_SL + ((1*NB + b)*NC + c)*64 + l] = lo;
        }
#pragma unroll 1
        for (int j2 = 1; j2 <= NCHUNK - 2; ++j2) {
            float f = F_lds[(j2*NB + b)*64 + l];
            float a0 = f, a1 = 0.f, a2 = 0.f, a3 = 0.f;
#pragma unroll
            for (int m2 = 0; m2 < 64; m2 += 4) {
                a0 += aq[m2+0] * rdlane(s, m2+0);
                a1 += aq[m2+1] * rdlane(s, m2+1);
                a2 += aq[m2+2] * rdlane(s, m2+2);
                a3 += aq[m2+3] * rdlane(s, m2+3);
            }
            s = (a0 + a1) + (a2 + a3);
            unsigned short hi, lo; f2bf_hl(s, hi, lo);
            u16b[OFF_SH + (((j2+1)*NB + b)*NC + c)*64 + l] = hi;
            u16b[OFF_SL + (((j2+1)*NB + b)*NC + c)*64 + l] = lo;
        }
    }
}

// ---------------------------------------------------------------------------
// usadd: out += U @ S. 512 blocks x 256 thr, no LDS. Frags direct from global.
// ---------------------------------------------------------------------------
__global__ __launch_bounds__(256, 4) void usadd_kernel(const float* __restrict__ ws,
    float* __restrict__ out)
{
    const unsigned short* u16b = (const unsigned short*)(ws + U16_BASE);
    const int tid = threadIdx.x;
    const int c = blockIdx.x >> 2;
    const int g = blockIdx.x & 3;
    const int l = tid & 63;
    const int w = tid >> 6;
    const int lane2 = l & 31;
    const int h = l >> 5;
    const int m = w*32 + lane2;

    f32x16 c0[2] = {{}, {}}, c1[2] = {{}, {}}, c2[2] = {{}, {}};
#pragma unroll
    for (int t = 0; t < 4; ++t) {
        const unsigned short* up = u16b + (c*QC + m)*64 + 16*t + 8*h;
        bf16x8 ah = ld_frag(up + OFF_UH);
        bf16x8 al = ld_frag(up + OFF_UL);
#pragma unroll
        for (int nt = 0; nt < 2; ++nt) {
            int col = g*64 + nt*32 + lane2;
            int j = col >> 3, b = col & 7;
            const unsigned short* sp = u16b + ((j*NB + b)*NC + c)*64 + 16*t + 8*h;
            bf16x8 bh = ld_frag(sp + OFF_SH);
            bf16x8 bl = ld_frag(sp + OFF_SL);
            c0[nt] = __builtin_amdgcn_mfma_f32_32x32x16_bf16(ah, bh, c0[nt], 0, 0, 0);
            c1[nt] = __builtin_amdgcn_mfma_f32_32x32x16_bf16(al, bh, c1[nt], 0, 0, 0);
            c2[nt] = __builtin_amdgcn_mfma_f32_32x32x16_bf16(ah, bl, c2[nt], 0, 0, 0);
        }
    }
#pragma unroll
    for (int nt = 0; nt < 2; ++nt) {
        f32x16 s = (c0[nt] + c1[nt]) + c2[nt];
        int col = g*64 + nt*32 + lane2;
        int j = col >> 3, b = col & 7;
        float* op = out + ((long)(b*NC + c))*LSEQ + j*QC;
#pragma unroll
        for (int r = 0; r < 16; ++r) {
            int row = w*32 + (r & 3) + 8*(r >> 2) + 4*h;
            op[row] += s[r];
        }
    }
}

extern "C" void kernel_launch(void* const* d_in, const int* in_sizes, int n_in,
                              void* d_out, int out_size, void* d_ws, size_t ws_size,
                              hipStream_t stream)
{
    const float* signal = (const float*)d_in[0];
    const float* B      = (const float*)d_in[1];
    const float* C      = (const float*)d_in[2];
    const float* A      = (const float*)d_in[3];
    const float* dt     = (const float*)d_in[4];
    float* ws  = (float*)d_ws;
    float* out = (float*)d_out;

    hipLaunchKernelGGL(setup_kernel,  dim3(1),    dim3(1024), 0, stream, A, B, dt, ws);
    hipLaunchKernelGGL(chains_kernel, dim3(272),  dim3(256),  0, stream, C, ws);
    hipLaunchKernelGGL(fused_kernel,  dim3(NC),   dim3(512),  0, stream, signal, ws, out);
    hipLaunchKernelGGL(usadd_kernel,  dim3(NC*4), dim3(256),  0, stream, ws, out);
}

// Round 8
// 92.460 us; speedup vs baseline: 1.3831x; 1.3831x over previous
//
#include <hip/hip_runtime.h>

#define N 64
#define NC 128
#define NB 8
#define LSEQ 4096
#define QC 128
#define NCHUNK 32

// fp32 regions (float offsets into ws)
#define OFF_ABAR 0
#define OFF_AQ   4096
#define OFF_BBAR 8192          // [n][c] 64x128
#define OFF_ABT  16384
#define OFF_A4   20480
#define OFF_A4T  24576
#define OFF_FS   36864         // (reserved, unused)
#define U16_BASE (OFF_FS + NCHUNK*NB*NC*N)

// u16 offsets (in u16 units) relative to u16b = (unsigned short*)(ws + U16_BASE)
#define OFF_WH 0                       // [c][n][kq] 128x64x128, kq = 127-p
#define OFF_WL (OFF_WH + NC*N*QC)
#define OFF_UH (OFF_WL + NC*N*QC)      // [c][q][n]
#define OFF_UL (OFF_UH + NC*QC*N)
#define OFF_KH (OFF_UL + NC*QC*N)      // [c][256] reversed-extended k
#define OFF_KL (OFF_KH + NC*256)

typedef __attribute__((ext_vector_type(8)))  __bf16 bf16x8;
typedef __attribute__((ext_vector_type(16))) float  f32x16;
typedef __attribute__((ext_vector_type(4)))  unsigned int u32x4;

__device__ __forceinline__ float rdlane(float v, int l) {
    return __int_as_float(__builtin_amdgcn_readlane(__float_as_int(v), l));
}

__device__ __forceinline__ void load_row64(const float* __restrict__ p, float (&ar)[64]) {
    const float4* rp = reinterpret_cast<const float4*>(p);
#pragma unroll
    for (int t = 0; t < 16; ++t) {
        float4 v = rp[t];
        ar[4*t+0] = v.x; ar[4*t+1] = v.y; ar[4*t+2] = v.z; ar[4*t+3] = v.w;
    }
}

__device__ __forceinline__ float matvec64(const float (&ar)[64], float v) {
    float a0 = 0.f, a1 = 0.f, a2 = 0.f, a3 = 0.f;
#pragma unroll
    for (int m = 0; m < 64; m += 4) {
        a0 += ar[m+0] * rdlane(v, m+0);
        a1 += ar[m+1] * rdlane(v, m+1);
        a2 += ar[m+2] * rdlane(v, m+2);
        a3 += ar[m+3] * rdlane(v, m+3);
    }
    return (a0 + a1) + (a2 + a3);
}

// fp32 -> (hi, lo) bf16 pair, RNE both
__device__ __forceinline__ void f2bf_hl(float x, unsigned short& hi, unsigned short& lo) {
    unsigned u = __float_as_uint(x);
    unsigned r = (u + 0x7fffu + ((u >> 16) & 1u)) >> 16;
    hi = (unsigned short)r;
    float fh = __uint_as_float(r << 16);
    float l  = x - fh;
    unsigned ul = __float_as_uint(l);
    unsigned rl = (ul + 0x7fffu + ((ul >> 16) & 1u)) >> 16;
    lo = (unsigned short)rl;
}

__device__ __forceinline__ unsigned pack_hl2(float x0, float x1, unsigned& lo32) {
    unsigned short h0, l0, h1, l1;
    f2bf_hl(x0, h0, l0); f2bf_hl(x1, h1, l1);
    lo32 = (unsigned)l0 | ((unsigned)l1 << 16);
    return (unsigned)h0 | ((unsigned)h1 << 16);
}

__device__ __forceinline__ bf16x8 ld_frag(const unsigned short* p) {
    u32x4 v = *(const u32x4*)p;
    return __builtin_bit_cast(bf16x8, v);
}

__device__ __forceinline__ bf16x8 pack8(const unsigned short* v) {
    u32x4 u;
    u.x = v[0] | ((unsigned)v[1] << 16);
    u.y = v[2] | ((unsigned)v[3] << 16);
    u.z = v[4] | ((unsigned)v[5] << 16);
    u.w = v[6] | ((unsigned)v[7] << 16);
    return __builtin_bit_cast(bf16x8, u);
}

// ---------------------------------------------------------------------------
// setup: single block, 1024 threads. A_bar solves; A^2; B_bar; A^4. (verified R7)
// ---------------------------------------------------------------------------
__global__ __launch_bounds__(1024) void setup_kernel(const float* __restrict__ A,
    const float* __restrict__ B, const float* __restrict__ dtp, float* __restrict__ ws)
{
    __shared__ float AT[64*65];    // A^T; reused as A2 (row-major) in stage2
    __shared__ float Ab[64*65];
    __shared__ float AbT[64*65];
    __shared__ float A2T[64*65];
    const int tid = threadIdx.x;
    const int wv  = tid >> 6;
    const int l   = tid & 63;
    const float dt = dtp[0];
    const float h  = 0.5f * dt;

    for (int idx = tid; idx < 4096; idx += 1024) {
        int row = idx >> 6, i = idx & 63;
        AT[i*65 + row] = A[idx];
    }
    __syncthreads();
    const float rdv = 1.0f / (1.0f - h * AT[l*65 + l]);

#pragma unroll 1
    for (int rep = 0; rep < 4; ++rep) {
        const int j = wv + rep*16;
        float r = ((l == j) ? 1.0f : 0.0f) + h * AT[j*65 + l];
#pragma unroll
        for (int i = 0; i < 64; ++i) {
            float xi = rdlane(r, i) * rdlane(rdv, i);
            r = fmaf(h * xi, AT[i*65 + l], r);
            r = (l == i) ? xi : r;
        }
        Ab[l*65 + j]  = r;
        AbT[j*65 + l] = r;
    }
    __syncthreads();

    for (int idx = tid; idx < 4096; idx += 1024) {
        int i = idx >> 6, j = idx & 63;
        ws[OFF_ABAR + idx] = Ab[i*65 + j];
        ws[OFF_ABT + idx]  = AbT[i*65 + j];
    }
    float ar[64];
#pragma unroll
    for (int m2 = 0; m2 < 64; ++m2) ar[m2] = Ab[l*65 + m2];

#pragma unroll 1
    for (int rep = 0; rep < 4; ++rep) {
        const int j = wv + rep*16;
        float v = AbT[j*65 + l];
        float y = matvec64(ar, v);
        AT[l*65 + j]  = y;
        A2T[j*65 + l] = y;
    }
#pragma unroll 1
    for (int rep = 0; rep < 8; ++rep) {
        const int c = wv + rep*16;
        float v = B[l*NC + c];
        float y = matvec64(ar, v);
        ws[OFF_BBAR + l*NC + c] = h * (y + v);
    }
    __syncthreads();

    float a2r[64];
#pragma unroll
    for (int m2 = 0; m2 < 64; ++m2) a2r[m2] = AT[l*65 + m2];
#pragma unroll 1
    for (int rep = 0; rep < 4; ++rep) {
        const int j = wv + rep*16;
        float v = A2T[j*65 + l];
        float y = matvec64(a2r, v);
        ws[OFF_A4 + l*64 + j]  = y;
        ws[OFF_A4T + j*64 + l] = y;
    }
}

// ---------------------------------------------------------------------------
// chains: stride-4 chains with A^4 / (A^4)^T. 4 waves per block. (verified R7)
// ---------------------------------------------------------------------------
__global__ __launch_bounds__(256, 1) void chains_kernel(const float* __restrict__ C,
    float* __restrict__ ws)
{
    __shared__ float Wlds[128][65];
    __shared__ float karr[128];
    __shared__ float seed[3][64];
    unsigned short* u16b = (unsigned short*)(ws + U16_BASE);
    const int bid = blockIdx.x;
    const int tid = threadIdx.x;
    const int w4  = tid >> 6;
    const int l   = tid & 63;

    if (bid < 128) {                       // ---- W chain + k, channel c
        const int c = bid;
        float a4[64];
        load_row64(ws + OFF_A4 + l*64, a4);
        const float Cl = C[l*NC + c];
        float cur;
        if (w4 == 0) {
            float ab[64];
            load_row64(ws + OFF_ABAR + l*64, ab);
            float t = ws[OFF_BBAR + l*NC + c];
            cur = t;
            t = matvec64(ab, t); seed[0][l] = t;
            t = matvec64(ab, t); seed[1][l] = t;
            t = matvec64(ab, t); seed[2][l] = t;
        }
        __syncthreads();
        if (w4 > 0) cur = seed[w4 - 1][l];
        int p = w4;
#pragma unroll 1
        for (int it = 0; it < 32; ++it) {
            Wlds[p][l] = cur;
            float d = Cl * cur;
            d += __shfl_xor(d, 32, 64); d += __shfl_xor(d, 16, 64);
            d += __shfl_xor(d, 8, 64);  d += __shfl_xor(d, 4, 64);
            d += __shfl_xor(d, 2, 64);  d += __shfl_xor(d, 1, 64);
            if (l == 0) karr[p] = d;
            if (it < 31) { cur = matvec64(a4, cur); p += 4; }
        }
        __syncthreads();
        for (int idx = tid; idx < 64*64; idx += 256) {
            int n = idx >> 6, i2 = idx & 63;
            int kq = i2*2;
            float w0 = Wlds[127 - kq][n];
            float w1 = Wlds[126 - kq][n];
            unsigned lo32, hi32 = pack_hl2(w0, w1, lo32);
            ((unsigned*)(u16b + OFF_WH + (c*64 + n)*128))[i2] = hi32;
            ((unsigned*)(u16b + OFF_WL + (c*64 + n)*128))[i2] = lo32;
        }
        if (tid < 128) {
            int i = tid;
            float k0 = (2*i   < 128) ? karr[127 - 2*i] : 0.0f;
            float k1 = (2*i+1 < 128) ? karr[126 - 2*i] : 0.0f;
            unsigned lo32, hi32 = pack_hl2(k0, k1, lo32);
            ((unsigned*)(u16b + OFF_KH + c*256))[i] = hi32;
            ((unsigned*)(u16b + OFF_KL + c*256))[i] = lo32;
        }
    } else if (bid < 256) {                // ---- U chain, channel c
        const int c = bid - 128;
        float a4t[64];
        load_row64(ws + OFF_A4T + l*64, a4t);
        float cur;
        if (w4 == 0) {
            float abt[64];
            load_row64(ws + OFF_ABT + l*64, abt);
            float t = C[l*NC + c];
            t = matvec64(abt, t); cur = t;
            t = matvec64(abt, t); seed[0][l] = t;
            t = matvec64(abt, t); seed[1][l] = t;
            t = matvec64(abt, t); seed[2][l] = t;
        }
        __syncthreads();
        if (w4 > 0) cur = seed[w4 - 1][l];
        int q = w4;
#pragma unroll 1
        for (int it = 0; it < 32; ++it) {
            unsigned short hi, lo; f2bf_hl(cur, hi, lo);
            u16b[OFF_UH + (c*QC + q)*64 + l] = hi;
            u16b[OFF_UL + (c*QC + q)*64 + l] = lo;
            if (it < 31) { cur = matvec64(a4t, cur); q += 4; }
        }
    } else {                               // ---- AQ columns (fp32)
        const int j = (bid - 256)*4 + w4;
        float a4[64];
        load_row64(ws + OFF_A4 + l*64, a4);
        float cur = (l == j) ? 1.0f : 0.0f;
#pragma unroll 1
        for (int it = 0; it < 32; ++it) cur = matvec64(a4, cur);
        ws[OFF_AQ + l*64 + j] = cur;
    }
}

// ---------------------------------------------------------------------------
// mega2: block = (c, b), 1024 blocks x 256 thr (4 waves), ~35 KB LDS (4/CU).
//   stage X(c,b) once -> bf16 hi/lo LDS
//   P1: waves 0,1: F = Wrev@X -> F_lds; all waves: conv = T@X (m-tile w) in regs
//   P2: wave 3: 32-step scan from F_lds -> S_lds (bf16 hi/lo)
//   P3: all waves: acc += U@S (C-in chaining); single out write
// ---------------------------------------------------------------------------
__global__ __launch_bounds__(256, 4) void mega2_kernel(const float* __restrict__ x,
    const float* __restrict__ ws, float* __restrict__ out)
{
    __shared__ __align__(16) unsigned Xh32[32*68], Xl32[32*68];
    __shared__ __align__(16) unsigned krh32[128], krl32[128];
    __shared__ float F_lds[32*65];
    __shared__ __align__(16) unsigned short SH_lds[32*72], SL_lds[32*72];

    const unsigned short* u16b = (const unsigned short*)(ws + U16_BASE);
    const int tid = threadIdx.x;
    const int c = blockIdx.x >> 3;
    const int b = blockIdx.x & 7;
    const int w = tid >> 6;
    const int l = tid & 63;
    const int lane2 = l & 31;
    const int h = l >> 5;

    if (tid < 128) {
        krh32[tid] = ((const unsigned*)(u16b + OFF_KH + c*256))[tid];
        krl32[tid] = ((const unsigned*)(u16b + OFF_KL + c*256))[tid];
    }
    for (int idx = tid; idx < 32*64; idx += 256) {
        int col = idx >> 6, i2 = idx & 63;            // col = chunk j
        const float2 xv = *reinterpret_cast<const float2*>(
            x + ((long)(b*NC + c))*LSEQ + col*QC + i2*2);
        unsigned lo32, hi32 = pack_hl2(xv.x, xv.y, lo32);
        Xh32[col*68 + i2] = hi32;
        Xl32[col*68 + i2] = lo32;
    }
    __syncthreads();

    const unsigned short* Xh = (const unsigned short*)Xh32;
    const unsigned short* Xl = (const unsigned short*)Xl32;
    const unsigned short* krh = (const unsigned short*)krh32;
    const unsigned short* krl = (const unsigned short*)krl32;

    // ---- P1a: waves 0,1: F quadrant mt = w (rows n = mt*32..mt*32+31, cols j)
    if (w < 2) {
        const int mt = w;
        const unsigned short* WHp = u16b + OFF_WH + (c*64 + mt*32 + lane2)*128 + 8*h;
        const unsigned short* WLp = u16b + OFF_WL + (c*64 + mt*32 + lane2)*128 + 8*h;
        f32x16 f0 = {}, f1 = {}, f2 = {};
#pragma unroll
        for (int t = 0; t < 8; ++t) {
            bf16x8 ah = ld_frag(WHp + 16*t);
            bf16x8 al = ld_frag(WLp + 16*t);
            bf16x8 bh = ld_frag(&Xh[lane2*136 + 16*t + 8*h]);
            bf16x8 bl = ld_frag(&Xl[lane2*136 + 16*t + 8*h]);
            f0 = __builtin_amdgcn_mfma_f32_32x32x16_bf16(ah, bh, f0, 0, 0, 0);
            f1 = __builtin_amdgcn_mfma_f32_32x32x16_bf16(al, bh, f1, 0, 0, 0);
            f2 = __builtin_amdgcn_mfma_f32_32x32x16_bf16(ah, bl, f2, 0, 0, 0);
        }
        f32x16 s = f0 + f1 + f2;
#pragma unroll
        for (int r = 0; r < 16; ++r) {
            int n = mt*32 + (r & 3) + 8*(r >> 2) + 4*h;
            F_lds[lane2*65 + n] = s[r];      // col(lane2)=j, conflict-free (stride 65)
        }
    }

    // ---- P1b: all waves: conv m-tile w (rows q = w*32..w*32+31)
    f32x16 conv;
    {
        const int m = w*32 + lane2;
        f32x16 a0 = {}, a1 = {}, a2 = {};
#pragma unroll
        for (int t = 0; t < 8; ++t) {
            int I0 = 127 - m + 16*t + 8*h;
            unsigned short vh[8], vl[8];
#pragma unroll
            for (int e = 0; e < 8; ++e) { vh[e] = krh[I0 + e]; vl[e] = krl[I0 + e]; }
            bf16x8 ah = pack8(vh), al = pack8(vl);
            bf16x8 bh = ld_frag(&Xh[lane2*136 + 16*t + 8*h]);
            bf16x8 bl = ld_frag(&Xl[lane2*136 + 16*t + 8*h]);
            a0 = __builtin_amdgcn_mfma_f32_32x32x16_bf16(ah, bh, a0, 0, 0, 0);
            a1 = __builtin_amdgcn_mfma_f32_32x32x16_bf16(al, bh, a1, 0, 0, 0);
            a2 = __builtin_amdgcn_mfma_f32_32x32x16_bf16(ah, bl, a2, 0, 0, 0);
        }
        conv = a0 + a1 + a2;
    }
    __syncthreads();

    // ---- P2: wave 3: scan S_{j+1} = AQ S_j + F_j (S_0 = 0), slots 0..31 = S_j
    if (w == 3) {
        float aq[64];
        load_row64(ws + OFF_AQ + l*64, aq);
        SH_lds[0*72 + l] = 0; SL_lds[0*72 + l] = 0;
        float s = F_lds[0*65 + l];                     // S_1 = F_0
        { unsigned short hi, lo; f2bf_hl(s, hi, lo);
          SH_lds[1*72 + l] = hi; SL_lds[1*72 + l] = lo; }
#pragma unroll 1
        for (int j2 = 1; j2 <= 30; ++j2) {
            float f = F_lds[j2*65 + l];
            float a0 = f, a1 = 0.f, a2 = 0.f, a3 = 0.f;
#pragma unroll
            for (int m2 = 0; m2 < 64; m2 += 4) {
                a0 += aq[m2+0] * rdlane(s, m2+0);
                a1 += aq[m2+1] * rdlane(s, m2+1);
                a2 += aq[m2+2] * rdlane(s, m2+2);
                a3 += aq[m2+3] * rdlane(s, m2+3);
            }
            s = (a0 + a1) + (a2 + a3);
            unsigned short hi, lo; f2bf_hl(s, hi, lo);
            SH_lds[(j2+1)*72 + l] = hi; SL_lds[(j2+1)*72 + l] = lo;
        }
    }
    __syncthreads();

    // ---- P3: all waves: acc += U @ S (K=64), write out
    {
        const int m = w*32 + lane2;
        f32x16 a0 = conv, a1 = {}, a2 = {};
#pragma unroll
        for (int t = 0; t < 4; ++t) {
            const unsigned short* up = u16b + (c*QC + m)*64 + 16*t + 8*h;
            bf16x8 ah = ld_frag(up + OFF_UH);
            bf16x8 al = ld_frag(up + OFF_UL);
            bf16x8 bh = ld_frag(&SH_lds[lane2*72 + 16*t + 8*h]);
            bf16x8 bl = ld_frag(&SL_lds[lane2*72 + 16*t + 8*h]);
            a0 = __builtin_amdgcn_mfma_f32_32x32x16_bf16(ah, bh, a0, 0, 0, 0);
            a1 = __builtin_amdgcn_mfma_f32_32x32x16_bf16(al, bh, a1, 0, 0, 0);
            a2 = __builtin_amdgcn_mfma_f32_32x32x16_bf16(ah, bl, a2, 0, 0, 0);
        }
        f32x16 s = (a0 + a1) + a2;
        float* op = out + ((long)(b*NC + c))*LSEQ + lane2*QC;  // col = j = lane2
#pragma unroll
        for (int r = 0; r < 16; ++r) {
            int row = w*32 + (r & 3) + 8*(r >> 2) + 4*h;
            op[row] = s[r];
        }
    }
}

extern "C" void kernel_launch(void* const* d_in, const int* in_sizes, int n_in,
                              void* d_out, int out_size, void* d_ws, size_t ws_size,
                              hipStream_t stream)
{
    const float* signal = (const float*)d_in[0];
    const float* B      = (const float*)d_in[1];
    const float* C      = (const float*)d_in[2];
    const float* A      = (const float*)d_in[3];
    const float* dt     = (const float*)d_in[4];
    float* ws  = (float*)d_ws;
    float* out = (float*)d_out;

    hipLaunchKernelGGL(setup_kernel,  dim3(1),     dim3(1024), 0, stream, A, B, dt, ws);
    hipLaunchKernelGGL(chains_kernel, dim3(272),   dim3(256),  0, stream, C, ws);
    hipLaunchKernelGGL(mega2_kernel,  dim3(NC*NB), dim3(256),  0, stream, signal, ws, out);
}